// Round 1
// baseline (407.594 us; speedup 1.0000x reference)
//
#include <hip/hip_runtime.h>

#define HID   2048
#define KD    2048
#define GQ    4
#define HPGQ  4
#define DH    128
#define SEQ   2048
#define NBATCH 2
#define NTOK  (NBATCH * SEQ)   // 4096
#define NQKV  3072

typedef unsigned short u16;
typedef unsigned int   u32;
using bf16x8 = __attribute__((ext_vector_type(8))) __bf16;
using f32x4  = __attribute__((ext_vector_type(4))) float;

__device__ __forceinline__ u16 f2bf(float f) {
  union { float f; u32 u; } v; v.f = f;
  u32 u = v.u + 0x7fffu + ((v.u >> 16) & 1u);
  return (u16)(u >> 16);
}

__device__ __forceinline__ void gl16(const void* g, void* l) {
  __builtin_amdgcn_global_load_lds((const __attribute__((address_space(1))) u32*)g,
                                   (__attribute__((address_space(3))) u32*)l, 16, 0, 0);
}

// ---------------- fp32 -> bf16 elementwise convert (x) ----------------
__global__ __launch_bounds__(256) void k_cvt_bf16(const float* __restrict__ in,
                                                  u16* __restrict__ out, int n4) {
  int i = blockIdx.x * 256 + threadIdx.x;
  if (i < n4) {
    const float4 v = ((const float4*)in)[i];
    ushort4 o;
    o.x = f2bf(v.x); o.y = f2bf(v.y); o.z = f2bf(v.z); o.w = f2bf(v.w);
    ((ushort4*)out)[i] = o;
  }
}

// ---------------- fp32 (K x N) -> bf16 transposed (N x K) ----------------
__global__ __launch_bounds__(256) void k_trans_cvt(const float* __restrict__ W,
                                                   u16* __restrict__ WT,
                                                   int K, int N, int rowoff) {
  __shared__ float tile[32][33];
  const int tx = threadIdx.x, ty = threadIdx.y;
  const int k0 = blockIdx.y * 32, n0 = blockIdx.x * 32;
#pragma unroll
  for (int i = 0; i < 4; ++i)
    tile[ty + 8 * i][tx] = W[(size_t)(k0 + ty + 8 * i) * N + (n0 + tx)];
  __syncthreads();
#pragma unroll
  for (int i = 0; i < 4; ++i)
    WT[(size_t)(rowoff + n0 + ty + 8 * i) * K + (k0 + tx)] = f2bf(tile[tx][ty + 8 * i]);
}

// ---------------- QKV GEMM: x(4096x2048) @ [Wq|Wk|Wv]^T -> qkv bf16, v scattered as V^T ----
__global__ __launch_bounds__(256) void k_gemm_qkv(
    const u16* __restrict__ A, const u16* __restrict__ Bt,
    u16* __restrict__ qkv, u16* __restrict__ vT,
    const float* __restrict__ bq, const float* __restrict__ bk,
    const float* __restrict__ bv) {
  __shared__ u16 As[128 * 32];
  __shared__ u16 Bs[128 * 32];
  const int t = threadIdx.x, l = t & 63, w = t >> 6;
  const int lr = l & 15, lk = l >> 4;
  const int wr = w >> 1, wc = w & 1;
  const int m0 = blockIdx.y * 128, n0 = blockIdx.x * 128;

  f32x4 acc[4][4] = {};

  for (int kt = 0; kt < KD / 32; ++kt) {
    const int k0 = kt * 32;
#pragma unroll
    for (int i = 0; i < 2; ++i) {
      const int e = i * 256 + t;
      const int r = e >> 2, c = (e & 3) << 3;
      gl16(A  + (size_t)(m0 + r) * KD + k0 + c, As + e * 8);
      gl16(Bt + (size_t)(n0 + r) * KD + k0 + c, Bs + e * 8);
    }
    __syncthreads();
    bf16x8 af[4], bfr[4];
#pragma unroll
    for (int m = 0; m < 4; ++m)
      af[m] = *(const bf16x8*)(As + (wr * 64 + m * 16 + lr) * 32 + lk * 8);
#pragma unroll
    for (int n = 0; n < 4; ++n)
      bfr[n] = *(const bf16x8*)(Bs + (wc * 64 + n * 16 + lr) * 32 + lk * 8);
#pragma unroll
    for (int m = 0; m < 4; ++m)
#pragma unroll
      for (int n = 0; n < 4; ++n)
        acc[m][n] = __builtin_amdgcn_mfma_f32_16x16x32_bf16(af[m], bfr[n], acc[m][n], 0, 0, 0);
    __syncthreads();
  }

  const int gm = m0 + wr * 64, gn = n0 + wc * 64;
#pragma unroll
  for (int m = 0; m < 4; ++m) {
    const int row0 = gm + m * 16 + lk * 4;
#pragma unroll
    for (int n = 0; n < 4; ++n) {
      const int col = gn + n * 16 + lr;
      float bias;
      if (col < HID) bias = bq[col];
      else if (col < HID + 512) bias = bk[col - HID];
      else bias = bv[col - HID - 512];
      if (col < HID + 512) {
#pragma unroll
        for (int r = 0; r < 4; ++r)
          qkv[(size_t)(row0 + r) * NQKV + col] = f2bf(acc[m][n][r] + bias);
      } else {
        const int gg = (col - 2560) >> 7, d = (col - 2560) & 127;
        const int b = row0 >> 11, s0 = row0 & 2047;
        ushort4 pk;
        pk.x = f2bf(acc[m][n][0] + bias);
        pk.y = f2bf(acc[m][n][1] + bias);
        pk.z = f2bf(acc[m][n][2] + bias);
        pk.w = f2bf(acc[m][n][3] + bias);
        *(ushort4*)(vT + ((size_t)(b * GQ + gg) * DH + d) * SEQ + s0) = pk;
      }
    }
  }
}

// ---------------- O projection GEMM: o(4096x2048) @ Wo^T + bo -> fp32 out ----------------
__global__ __launch_bounds__(256) void k_gemm_o(
    const u16* __restrict__ A, const u16* __restrict__ Bt,
    const float* __restrict__ bo, float* __restrict__ C) {
  __shared__ u16 As[128 * 32];
  __shared__ u16 Bs[128 * 32];
  const int t = threadIdx.x, l = t & 63, w = t >> 6;
  const int lr = l & 15, lk = l >> 4;
  const int wr = w >> 1, wc = w & 1;
  const int m0 = blockIdx.y * 128, n0 = blockIdx.x * 128;

  f32x4 acc[4][4] = {};

  for (int kt = 0; kt < KD / 32; ++kt) {
    const int k0 = kt * 32;
#pragma unroll
    for (int i = 0; i < 2; ++i) {
      const int e = i * 256 + t;
      const int r = e >> 2, c = (e & 3) << 3;
      gl16(A  + (size_t)(m0 + r) * KD + k0 + c, As + e * 8);
      gl16(Bt + (size_t)(n0 + r) * KD + k0 + c, Bs + e * 8);
    }
    __syncthreads();
    bf16x8 af[4], bfr[4];
#pragma unroll
    for (int m = 0; m < 4; ++m)
      af[m] = *(const bf16x8*)(As + (wr * 64 + m * 16 + lr) * 32 + lk * 8);
#pragma unroll
    for (int n = 0; n < 4; ++n)
      bfr[n] = *(const bf16x8*)(Bs + (wc * 64 + n * 16 + lr) * 32 + lk * 8);
#pragma unroll
    for (int m = 0; m < 4; ++m)
#pragma unroll
      for (int n = 0; n < 4; ++n)
        acc[m][n] = __builtin_amdgcn_mfma_f32_16x16x32_bf16(af[m], bfr[n], acc[m][n], 0, 0, 0);
    __syncthreads();
  }

  const int gm = m0 + wr * 64, gn = n0 + wc * 64;
#pragma unroll
  for (int m = 0; m < 4; ++m) {
    const int row0 = gm + m * 16 + lk * 4;
#pragma unroll
    for (int n = 0; n < 4; ++n) {
      const int col = gn + n * 16 + lr;
      const float bias = bo[col];
#pragma unroll
      for (int r = 0; r < 4; ++r)
        C[(size_t)(row0 + r) * HID + col] = acc[m][n][r] + bias;
    }
  }
}

// ---------------- Flash attention: per block one (b,g,h) and 128 q-rows ----------------
__global__ __launch_bounds__(256) void k_attn(
    const u16* __restrict__ qkv, const u16* __restrict__ vT, u16* __restrict__ o_ws) {
  __shared__ u16 Qs[128 * 128];
  __shared__ u16 Ks[64 * 128];
  __shared__ u16 Vs[128 * 64];
  __shared__ u16 Ps[128 * 64];

  const int t = threadIdx.x, l = t & 63, w = t >> 6;
  const int lr = l & 15, lk = l >> 4;
  const int bgh = blockIdx.y;
  const int b = bgh >> 4, g = (bgh >> 2) & 3, h = bgh & 3;
  const int q0 = blockIdx.x * 128;
  const int qcol = (g * HPGQ + h) * DH;

#pragma unroll
  for (int i = 0; i < 8; ++i) {
    const int e = i * 256 + t;
    const int r = e >> 4, c = (e & 15) << 3;
    gl16(qkv + (size_t)(b * SEQ + q0 + r) * NQKV + qcol + c, Qs + e * 8);
  }
  __syncthreads();
  bf16x8 qf[2][4];
#pragma unroll
  for (int m = 0; m < 2; ++m)
#pragma unroll
    for (int kk = 0; kk < 4; ++kk)
      qf[m][kk] = *(const bf16x8*)(Qs + (w * 32 + m * 16 + lr) * 128 + kk * 32 + lk * 8);

  f32x4 acc_o[2][8] = {};
  float rm[2][4], rl[2][4];
#pragma unroll
  for (int m = 0; m < 2; ++m)
#pragma unroll
    for (int r = 0; r < 4; ++r) { rm[m][r] = -3.0e38f; rl[m][r] = 0.f; }

  const float scale = 0.08838834764831845f;  // 1/sqrt(128)

  for (int tt = 0; tt < SEQ / 64; ++tt) {
    const int t0 = tt * 64;
    __syncthreads();
#pragma unroll
    for (int i = 0; i < 4; ++i) {
      const int e = i * 256 + t;
      const int r = e >> 4, c = (e & 15) << 3;
      gl16(qkv + (size_t)(b * SEQ + t0 + r) * NQKV + HID + g * DH + c, Ks + e * 8);
      const int rv = e >> 3, cv = (e & 7) << 3;
      gl16(vT + ((size_t)(b * GQ + g) * DH + rv) * SEQ + t0 + cv, Vs + e * 8);
    }
    __syncthreads();

    // scores = Q K^T
    f32x4 sc[2][4] = {};
#pragma unroll
    for (int kk = 0; kk < 4; ++kk) {
      bf16x8 kf[4];
#pragma unroll
      for (int n = 0; n < 4; ++n)
        kf[n] = *(const bf16x8*)(Ks + (n * 16 + lr) * 128 + kk * 32 + lk * 8);
#pragma unroll
      for (int m = 0; m < 2; ++m)
#pragma unroll
        for (int n = 0; n < 4; ++n)
          sc[m][n] = __builtin_amdgcn_mfma_f32_16x16x32_bf16(qf[m][kk], kf[n], sc[m][n], 0, 0, 0);
    }

    // online softmax (per q-row; row lives in a 16-lane group)
#pragma unroll
    for (int m = 0; m < 2; ++m) {
#pragma unroll
      for (int r = 0; r < 4; ++r) {
        float mx = fmaxf(fmaxf(sc[m][0][r], sc[m][1][r]),
                         fmaxf(sc[m][2][r], sc[m][3][r])) * scale;
#pragma unroll
        for (int off = 1; off < 16; off <<= 1) mx = fmaxf(mx, __shfl_xor(mx, off));
        const float mnew = fmaxf(rm[m][r], mx);
        const float alpha = __expf(rm[m][r] - mnew);
        rm[m][r] = mnew;
        float rs = 0.f;
#pragma unroll
        for (int n = 0; n < 4; ++n) {
          const float p = __expf(sc[m][n][r] * scale - mnew);
          sc[m][n][r] = p;
          rs += p;
        }
#pragma unroll
        for (int off = 1; off < 16; off <<= 1) rs += __shfl_xor(rs, off);
        rl[m][r] = rl[m][r] * alpha + rs;
#pragma unroll
        for (int nd = 0; nd < 8; ++nd) acc_o[m][nd][r] *= alpha;
      }
    }

    // P -> LDS (wave-private region)
#pragma unroll
    for (int m = 0; m < 2; ++m)
#pragma unroll
      for (int n = 0; n < 4; ++n)
#pragma unroll
        for (int r = 0; r < 4; ++r)
          Ps[(w * 32 + m * 16 + lk * 4 + r) * 64 + n * 16 + lr] = f2bf(sc[m][n][r]);

    // O += P V
#pragma unroll
    for (int kk = 0; kk < 2; ++kk) {
      bf16x8 pf[2];
#pragma unroll
      for (int m = 0; m < 2; ++m)
        pf[m] = *(const bf16x8*)(Ps + (w * 32 + m * 16 + lr) * 64 + kk * 32 + lk * 8);
#pragma unroll
      for (int nd = 0; nd < 8; ++nd) {
        const bf16x8 vf = *(const bf16x8*)(Vs + (nd * 16 + lr) * 64 + kk * 32 + lk * 8);
#pragma unroll
        for (int m = 0; m < 2; ++m)
          acc_o[m][nd] = __builtin_amdgcn_mfma_f32_16x16x32_bf16(pf[m], vf, acc_o[m][nd], 0, 0, 0);
      }
    }
  }

#pragma unroll
  for (int m = 0; m < 2; ++m)
#pragma unroll
    for (int nd = 0; nd < 8; ++nd)
#pragma unroll
      for (int r = 0; r < 4; ++r) {
        const int q = q0 + w * 32 + m * 16 + lk * 4 + r;
        const int d = nd * 16 + lr;
        o_ws[(size_t)(b * SEQ + q) * HID + qcol + d] = f2bf(acc_o[m][nd][r] / rl[m][r]);
      }
}

extern "C" void kernel_launch(void* const* d_in, const int* in_sizes, int n_in,
                              void* d_out, int out_size, void* d_ws, size_t ws_size,
                              hipStream_t stream) {
  const float* x  = (const float*)d_in[0];
  const float* Wq = (const float*)d_in[1];
  const float* bq = (const float*)d_in[2];
  const float* Wk = (const float*)d_in[3];
  const float* bk = (const float*)d_in[4];
  const float* Wv = (const float*)d_in[5];
  const float* bv = (const float*)d_in[6];
  const float* Wo = (const float*)d_in[7];
  const float* bo = (const float*)d_in[8];
  float* out = (float*)d_out;

  char* ws = (char*)d_ws;
  u16* x_bf  = (u16*)ws;  ws += (size_t)NTOK * KD * 2;        // 16 MiB (reused as o_ws later)
  u16* qkvT  = (u16*)ws;  ws += (size_t)NQKV * KD * 2;        // 12 MiB
  u16* WoT   = (u16*)ws;  ws += (size_t)HID * KD * 2;         //  8 MiB
  u16* qkv   = (u16*)ws;  ws += (size_t)NTOK * NQKV * 2;      // 24 MiB
  u16* vTb   = (u16*)ws;  ws += (size_t)NBATCH * GQ * DH * SEQ * 2;  // 4 MiB
  u16* o_ws  = x_bf;  // x_bf dead after QKV GEMM; attention output reuses it

  k_cvt_bf16<<<(NTOK * KD / 4 + 255) / 256, 256, 0, stream>>>(x, x_bf, NTOK * KD / 4);
  k_trans_cvt<<<dim3(HID / 32, KD / 32), dim3(32, 8), 0, stream>>>(Wq, qkvT, KD, HID, 0);
  k_trans_cvt<<<dim3(512 / 32, KD / 32), dim3(32, 8), 0, stream>>>(Wk, qkvT, KD, 512, 2048);
  k_trans_cvt<<<dim3(512 / 32, KD / 32), dim3(32, 8), 0, stream>>>(Wv, qkvT, KD, 512, 2560);
  k_trans_cvt<<<dim3(HID / 32, KD / 32), dim3(32, 8), 0, stream>>>(Wo, WoT, KD, HID, 0);

  k_gemm_qkv<<<dim3(NQKV / 128, NTOK / 128), 256, 0, stream>>>(x_bf, qkvT, qkv, vTb, bq, bk, bv);
  k_attn<<<dim3(SEQ / 128, NBATCH * GQ * HPGQ), 256, 0, stream>>>(qkv, vTb, o_ws);
  k_gemm_o<<<dim3(HID / 128, NTOK / 128), 256, 0, stream>>>(o_ws, WoT, bo, out);
}

// Round 2
// 388.252 us; speedup vs baseline: 1.0498x; 1.0498x over previous
//
#include <hip/hip_runtime.h>

#define HID   2048
#define KD    2048
#define GQ    4
#define HPGQ  4
#define DH    128
#define SEQ   2048
#define NBATCH 2
#define NTOK  (NBATCH * SEQ)   // 4096
#define NQKV  3072

typedef unsigned short u16;
typedef unsigned int   u32;
using bf16x8 = __attribute__((ext_vector_type(8))) __bf16;
using f32x4  = __attribute__((ext_vector_type(4))) float;

#if __has_builtin(__builtin_amdgcn_exp2f)
#define FEXP2(x) __builtin_amdgcn_exp2f(x)
#else
#define FEXP2(x) exp2f(x)
#endif

// 1/sqrt(128) * log2(e): folded into Q projection so scores are in log2 domain
#define QSCALE 0.12751744f

__device__ __forceinline__ u16 f2bf(float f) {
  union { float f; u32 u; } v; v.f = f;
  u32 u = v.u + 0x7fffu + ((v.u >> 16) & 1u);
  return (u16)(u >> 16);
}

__device__ __forceinline__ void gl16(const void* g, void* l) {
  __builtin_amdgcn_global_load_lds((const __attribute__((address_space(1))) u32*)g,
                                   (__attribute__((address_space(3))) u32*)l, 16, 0, 0);
}

// XOR-swizzle of the 16B-chunk index within a row; involution, applied to both
// the global source (staging) and the LDS read address (rule #21).
__device__ __forceinline__ int swz(int r, int c) {
  return (c & ~7) | ((c ^ r ^ (r >> 3)) & 7);
}

// ---------------- fp32 -> bf16 elementwise convert (x) ----------------
__global__ __launch_bounds__(256) void k_cvt_bf16(const float* __restrict__ in,
                                                  u16* __restrict__ out, int n4) {
  int i = blockIdx.x * 256 + threadIdx.x;
  if (i < n4) {
    const float4 v = ((const float4*)in)[i];
    ushort4 o;
    o.x = f2bf(v.x); o.y = f2bf(v.y); o.z = f2bf(v.z); o.w = f2bf(v.w);
    ((ushort4*)out)[i] = o;
  }
}

// ---------------- fp32 (K x N) -> bf16 transposed (N x K) ----------------
__global__ __launch_bounds__(256) void k_trans_cvt(const float* __restrict__ W,
                                                   u16* __restrict__ WT,
                                                   int K, int N, int rowoff) {
  __shared__ float tile[32][33];
  const int tx = threadIdx.x, ty = threadIdx.y;
  const int k0 = blockIdx.y * 32, n0 = blockIdx.x * 32;
#pragma unroll
  for (int i = 0; i < 4; ++i)
    tile[ty + 8 * i][tx] = W[(size_t)(k0 + ty + 8 * i) * N + (n0 + tx)];
  __syncthreads();
#pragma unroll
  for (int i = 0; i < 4; ++i)
    WT[(size_t)(rowoff + n0 + ty + 8 * i) * K + (k0 + tx)] = f2bf(tile[tx][ty + 8 * i]);
}

// ---------------- QKV GEMM: x(4096x2048) @ [Wq|Wk|Wv]^T -> qkv bf16, v scattered as V^T ----
__global__ __launch_bounds__(256) void k_gemm_qkv(
    const u16* __restrict__ A, const u16* __restrict__ Bt,
    u16* __restrict__ qkv, u16* __restrict__ vT,
    const float* __restrict__ bq, const float* __restrict__ bk,
    const float* __restrict__ bv) {
  __shared__ u16 As[128 * 32];
  __shared__ u16 Bs[128 * 32];
  const int t = threadIdx.x, l = t & 63, w = t >> 6;
  const int lr = l & 15, lk = l >> 4;
  const int wr = w >> 1, wc = w & 1;
  const int m0 = blockIdx.y * 128, n0 = blockIdx.x * 128;

  f32x4 acc[4][4] = {};

  for (int kt = 0; kt < KD / 32; ++kt) {
    const int k0 = kt * 32;
#pragma unroll
    for (int i = 0; i < 2; ++i) {
      const int e = i * 256 + t;
      const int r = e >> 2, c = (e & 3) << 3;
      gl16(A  + (size_t)(m0 + r) * KD + k0 + c, As + e * 8);
      gl16(Bt + (size_t)(n0 + r) * KD + k0 + c, Bs + e * 8);
    }
    __syncthreads();
    bf16x8 af[4], bfr[4];
#pragma unroll
    for (int m = 0; m < 4; ++m)
      af[m] = *(const bf16x8*)(As + (wr * 64 + m * 16 + lr) * 32 + lk * 8);
#pragma unroll
    for (int n = 0; n < 4; ++n)
      bfr[n] = *(const bf16x8*)(Bs + (wc * 64 + n * 16 + lr) * 32 + lk * 8);
#pragma unroll
    for (int m = 0; m < 4; ++m)
#pragma unroll
      for (int n = 0; n < 4; ++n)
        acc[m][n] = __builtin_amdgcn_mfma_f32_16x16x32_bf16(af[m], bfr[n], acc[m][n], 0, 0, 0);
    __syncthreads();
  }

  const int gm = m0 + wr * 64, gn = n0 + wc * 64;
#pragma unroll
  for (int m = 0; m < 4; ++m) {
    const int row0 = gm + m * 16 + lk * 4;
#pragma unroll
    for (int n = 0; n < 4; ++n) {
      const int col = gn + n * 16 + lr;
      float bias, qs = 1.0f;
      if (col < HID) { bias = bq[col]; qs = QSCALE; }
      else if (col < HID + 512) bias = bk[col - HID];
      else bias = bv[col - HID - 512];
      if (col < HID + 512) {
#pragma unroll
        for (int r = 0; r < 4; ++r)
          qkv[(size_t)(row0 + r) * NQKV + col] = f2bf((acc[m][n][r] + bias) * qs);
      } else {
        const int gg = (col - 2560) >> 7, d = (col - 2560) & 127;
        const int b = row0 >> 11, s0 = row0 & 2047;
        ushort4 pk;
        pk.x = f2bf(acc[m][n][0] + bias);
        pk.y = f2bf(acc[m][n][1] + bias);
        pk.z = f2bf(acc[m][n][2] + bias);
        pk.w = f2bf(acc[m][n][3] + bias);
        *(ushort4*)(vT + ((size_t)(b * GQ + gg) * DH + d) * SEQ + s0) = pk;
      }
    }
  }
}

// ---------------- O projection GEMM: o(4096x2048) @ Wo^T + bo -> fp32 out ----------------
__global__ __launch_bounds__(256) void k_gemm_o(
    const u16* __restrict__ A, const u16* __restrict__ Bt,
    const float* __restrict__ bo, float* __restrict__ C) {
  __shared__ u16 As[128 * 32];
  __shared__ u16 Bs[128 * 32];
  const int t = threadIdx.x, l = t & 63, w = t >> 6;
  const int lr = l & 15, lk = l >> 4;
  const int wr = w >> 1, wc = w & 1;
  const int m0 = blockIdx.y * 128, n0 = blockIdx.x * 128;

  f32x4 acc[4][4] = {};

  for (int kt = 0; kt < KD / 32; ++kt) {
    const int k0 = kt * 32;
#pragma unroll
    for (int i = 0; i < 2; ++i) {
      const int e = i * 256 + t;
      const int r = e >> 2, c = (e & 3) << 3;
      gl16(A  + (size_t)(m0 + r) * KD + k0 + c, As + e * 8);
      gl16(Bt + (size_t)(n0 + r) * KD + k0 + c, Bs + e * 8);
    }
    __syncthreads();
    bf16x8 af[4], bfr[4];
#pragma unroll
    for (int m = 0; m < 4; ++m)
      af[m] = *(const bf16x8*)(As + (wr * 64 + m * 16 + lr) * 32 + lk * 8);
#pragma unroll
    for (int n = 0; n < 4; ++n)
      bfr[n] = *(const bf16x8*)(Bs + (wc * 64 + n * 16 + lr) * 32 + lk * 8);
#pragma unroll
    for (int m = 0; m < 4; ++m)
#pragma unroll
      for (int n = 0; n < 4; ++n)
        acc[m][n] = __builtin_amdgcn_mfma_f32_16x16x32_bf16(af[m], bfr[n], acc[m][n], 0, 0, 0);
    __syncthreads();
  }

  const int gm = m0 + wr * 64, gn = n0 + wc * 64;
#pragma unroll
  for (int m = 0; m < 4; ++m) {
    const int row0 = gm + m * 16 + lk * 4;
#pragma unroll
    for (int n = 0; n < 4; ++n) {
      const int col = gn + n * 16 + lr;
      const float bias = bo[col];
#pragma unroll
      for (int r = 0; r < 4; ++r)
        C[(size_t)(row0 + r) * HID + col] = acc[m][n][r] + bias;
    }
  }
}

// ---------------- Flash attention ----------------
// 128 q-rows per block (32/wave), KV tiles of 64, K/V double-buffered (buffer 1
// aliases the dead Q region), all LDS tiles XOR-swizzled, row-sum via ones-column
// MFMA, deferred-max online softmax in log2 domain (scale pre-folded into Q).
__global__ __launch_bounds__(256) void k_attn(
    const u16* __restrict__ qkv, const u16* __restrict__ vT, u16* __restrict__ o_ws) {
  __shared__ u16 smem[40960];                 // 80 KiB -> 2 blocks/CU
  u16* const Qs  = smem;                      // 16384 elems; dead after q-frag hoist
  u16* const kb0 = smem + 16384;              // 8192
  u16* const vb0 = smem + 24576;              // 8192
  u16* const Ps  = smem + 32768;              // 8192 (wave-private slices)
  u16* const kb1 = smem;                      // aliases Qs
  u16* const vb1 = smem + 8192;

  const int t = threadIdx.x, l = t & 63, w = t >> 6;
  const int lr = l & 15, lk = l >> 4;
  const int bgh = blockIdx.y;
  const int b = bgh >> 4, g = (bgh >> 2) & 3, h = bgh & 3;
  const int q0 = blockIdx.x * 128;
  const int qcol = (g * HPGQ + h) * DH;
  const u16* qbase = qkv + (size_t)(b * SEQ) * NQKV;
  const u16* kbase = qbase + HID + g * DH;
  const u16* vbase = vT + (size_t)(b * GQ + g) * DH * SEQ;

  // stage Q (inverse-swizzled global source, linear LDS dest)
#pragma unroll
  for (int i = 0; i < 8; ++i) {
    const int e = i * 256 + t;
    const int r = e >> 4, c = e & 15;
    gl16(qbase + (size_t)(q0 + r) * NQKV + qcol + swz(r, c) * 8, Qs + e * 8);
  }
  // stage K/V tile 0 into buffer 0
  {
#pragma unroll
    for (int i = 0; i < 4; ++i) {
      const int e = i * 256 + t;
      const int r = e >> 4, c = e & 15;
      gl16(kbase + (size_t)r * NQKV + swz(r, c) * 8, kb0 + e * 8);
      const int rv = e >> 3, cv = e & 7;
      gl16(vbase + (size_t)rv * SEQ + swz(rv, cv) * 8, vb0 + e * 8);
    }
  }
  __syncthreads();

  // hoist Q fragments (swizzled read)
  bf16x8 qf[2][4];
#pragma unroll
  for (int m = 0; m < 2; ++m)
#pragma unroll
    for (int kk = 0; kk < 4; ++kk) {
      const int row = w * 32 + m * 16 + lr;
      qf[m][kk] = *(const bf16x8*)(Qs + row * 128 + swz(row, kk * 4 + lk) * 8);
    }
  __syncthreads();   // all waves done reading Q before buffer 1 overwrites it

  f32x4 acc_o[2][8] = {};
  f32x4 acc_s[2] = {};        // row-sum accumulator (valid at lr==0, col 0)
  float rm[2][4];
#pragma unroll
  for (int m = 0; m < 2; ++m)
#pragma unroll
    for (int r = 0; r < 4; ++r) rm[m][r] = -3.0e38f;

  bf16x8 vones;               // B-fragment: column 0 = ones -> row sums
#pragma unroll
  for (int j = 0; j < 8; ++j) vones[j] = (lr == 0) ? (__bf16)1.0f : (__bf16)0.0f;

  for (int tt = 0; tt < SEQ / 64; ++tt) {
    const u16* Ks = (tt & 1) ? kb1 : kb0;
    const u16* Vs = (tt & 1) ? vb1 : vb0;
    // issue next tile's staging into the other buffer (drained at end-of-iter barrier)
    if (tt < SEQ / 64 - 1) {
      const int t0 = (tt + 1) * 64;
      u16* kb = (tt & 1) ? kb0 : kb1;
      u16* vb = (tt & 1) ? vb0 : vb1;
#pragma unroll
      for (int i = 0; i < 4; ++i) {
        const int e = i * 256 + t;
        const int r = e >> 4, c = e & 15;
        gl16(kbase + (size_t)(t0 + r) * NQKV + swz(r, c) * 8, kb + e * 8);
        const int rv = e >> 3, cv = e & 7;
        gl16(vbase + (size_t)rv * SEQ + t0 + swz(rv, cv) * 8, vb + e * 8);
      }
    }

    // scores = Q K^T  (already in log2 domain; scale folded into Q)
    f32x4 sc[2][4] = {};
    __builtin_amdgcn_s_setprio(1);
#pragma unroll
    for (int kk = 0; kk < 4; ++kk) {
      bf16x8 kf[4];
#pragma unroll
      for (int n = 0; n < 4; ++n) {
        const int row = n * 16 + lr;
        kf[n] = *(const bf16x8*)(Ks + row * 128 + swz(row, kk * 4 + lk) * 8);
      }
#pragma unroll
      for (int m = 0; m < 2; ++m)
#pragma unroll
        for (int n = 0; n < 4; ++n)
          sc[m][n] = __builtin_amdgcn_mfma_f32_16x16x32_bf16(qf[m][kk], kf[n], sc[m][n], 0, 0, 0);
    }
    __builtin_amdgcn_s_setprio(0);

    // online softmax with deferred max (THR = 11.5 in log2 domain)
#pragma unroll
    for (int m = 0; m < 2; ++m) {
#pragma unroll
      for (int r = 0; r < 4; ++r) {
        float mx = fmaxf(fmaxf(sc[m][0][r], sc[m][1][r]),
                         fmaxf(sc[m][2][r], sc[m][3][r]));
#pragma unroll
        for (int off = 1; off < 16; off <<= 1) mx = fmaxf(mx, __shfl_xor(mx, off));
        if (mx > rm[m][r] + 11.5f) {
          const float al = FEXP2(rm[m][r] - mx);
          rm[m][r] = mx;
#pragma unroll
          for (int nd = 0; nd < 8; ++nd) acc_o[m][nd][r] *= al;
          acc_s[m][r] *= al;
        }
#pragma unroll
        for (int n = 0; n < 4; ++n)
          sc[m][n][r] = FEXP2(sc[m][n][r] - rm[m][r]);
      }
    }

    // P -> LDS (wave-private rows, swizzled)
#pragma unroll
    for (int m = 0; m < 2; ++m)
#pragma unroll
      for (int n = 0; n < 4; ++n)
#pragma unroll
        for (int r = 0; r < 4; ++r) {
          const int row = w * 32 + m * 16 + lk * 4 + r;
          const int col = n * 16 + lr;
          Ps[row * 64 + swz(row, col >> 3) * 8 + (col & 7)] = f2bf(sc[m][n][r]);
        }

    // O += P V ; row-sum += P · ones
    __builtin_amdgcn_s_setprio(1);
#pragma unroll
    for (int kk = 0; kk < 2; ++kk) {
      bf16x8 pf[2];
#pragma unroll
      for (int m = 0; m < 2; ++m) {
        const int row = w * 32 + m * 16 + lr;
        pf[m] = *(const bf16x8*)(Ps + row * 64 + swz(row, kk * 4 + lk) * 8);
      }
#pragma unroll
      for (int m = 0; m < 2; ++m)
        acc_s[m] = __builtin_amdgcn_mfma_f32_16x16x32_bf16(pf[m], vones, acc_s[m], 0, 0, 0);
#pragma unroll
      for (int nd = 0; nd < 8; ++nd) {
        const int rowv = nd * 16 + lr;
        const bf16x8 vf = *(const bf16x8*)(Vs + rowv * 64 + swz(rowv, kk * 4 + lk) * 8);
#pragma unroll
        for (int m = 0; m < 2; ++m)
          acc_o[m][nd] = __builtin_amdgcn_mfma_f32_16x16x32_bf16(pf[m], vf, acc_o[m][nd], 0, 0, 0);
      }
    }
    __builtin_amdgcn_s_setprio(0);

    __syncthreads();  // drains staging loads (vmcnt 0) + protects buffer swap
  }

  // epilogue: normalize by the MFMA-computed row sums
#pragma unroll
  for (int m = 0; m < 2; ++m)
#pragma unroll
    for (int r = 0; r < 4; ++r) {
      const float s = __shfl(acc_s[m][r], l & 48);
      const float inv = 1.0f / s;
      const int q = q0 + w * 32 + m * 16 + lk * 4 + r;
#pragma unroll
      for (int nd = 0; nd < 8; ++nd) {
        const int d = nd * 16 + lr;
        o_ws[(size_t)(b * SEQ + q) * HID + qcol + d] = f2bf(acc_o[m][nd][r] * inv);
      }
    }
}

extern "C" void kernel_launch(void* const* d_in, const int* in_sizes, int n_in,
                              void* d_out, int out_size, void* d_ws, size_t ws_size,
                              hipStream_t stream) {
  const float* x  = (const float*)d_in[0];
  const float* Wq = (const float*)d_in[1];
  const float* bq = (const float*)d_in[2];
  const float* Wk = (const float*)d_in[3];
  const float* bk = (const float*)d_in[4];
  const float* Wv = (const float*)d_in[5];
  const float* bv = (const float*)d_in[6];
  const float* Wo = (const float*)d_in[7];
  const float* bo = (const float*)d_in[8];
  float* out = (float*)d_out;

  char* ws = (char*)d_ws;
  u16* x_bf  = (u16*)ws;  ws += (size_t)NTOK * KD * 2;        // 16 MiB (reused as o_ws later)
  u16* qkvT  = (u16*)ws;  ws += (size_t)NQKV * KD * 2;        // 12 MiB
  u16* WoT   = (u16*)ws;  ws += (size_t)HID * KD * 2;         //  8 MiB
  u16* qkv   = (u16*)ws;  ws += (size_t)NTOK * NQKV * 2;      // 24 MiB
  u16* vTb   = (u16*)ws;  ws += (size_t)NBATCH * GQ * DH * SEQ * 2;  // 4 MiB
  u16* o_ws  = x_bf;  // x_bf dead after QKV GEMM; attention output reuses it

  k_cvt_bf16<<<(NTOK * KD / 4 + 255) / 256, 256, 0, stream>>>(x, x_bf, NTOK * KD / 4);
  k_trans_cvt<<<dim3(HID / 32, KD / 32), dim3(32, 8), 0, stream>>>(Wq, qkvT, KD, HID, 0);
  k_trans_cvt<<<dim3(512 / 32, KD / 32), dim3(32, 8), 0, stream>>>(Wk, qkvT, KD, 512, 2048);
  k_trans_cvt<<<dim3(512 / 32, KD / 32), dim3(32, 8), 0, stream>>>(Wv, qkvT, KD, 512, 2560);
  k_trans_cvt<<<dim3(HID / 32, KD / 32), dim3(32, 8), 0, stream>>>(Wo, WoT, KD, HID, 0);

  k_gemm_qkv<<<dim3(NQKV / 128, NTOK / 128), 256, 0, stream>>>(x_bf, qkvT, qkv, vTb, bq, bk, bv);
  k_attn<<<dim3(SEQ / 128, NBATCH * GQ * HPGQ), 256, 0, stream>>>(qkv, vTb, o_ws);
  k_gemm_o<<<dim3(HID / 128, NTOK / 128), 256, 0, stream>>>(o_ws, WoT, bo, out);
}

// Round 3
// 293.337 us; speedup vs baseline: 1.3895x; 1.3236x over previous
//
#include <hip/hip_runtime.h>

#define HID   2048
#define KD    2048
#define GQ    4
#define HPGQ  4
#define DH    128
#define SEQ   2048
#define NBATCH 2
#define NTOK  (NBATCH * SEQ)   // 4096
#define NQKV  3072

typedef unsigned short u16;
typedef unsigned int   u32;
using bf16x8 = __attribute__((ext_vector_type(8))) __bf16;
using bf16x2 = __attribute__((ext_vector_type(2))) __bf16;
using f32x4  = __attribute__((ext_vector_type(4))) float;
using u32x4  = __attribute__((ext_vector_type(4))) u32;

#if __has_builtin(__builtin_amdgcn_exp2f)
#define FEXP2(x) __builtin_amdgcn_exp2f(x)
#else
#define FEXP2(x) exp2f(x)
#endif

// 1/sqrt(128) * log2(e): folded into Q projection so scores are in log2 domain
#define QSCALE 0.12751744f

__device__ __forceinline__ u16 f2bf(float f) {
  union { float f; u32 u; } v; v.f = f;
  u32 u = v.u + 0x7fffu + ((v.u >> 16) & 1u);
  return (u16)(u >> 16);
}

// pack two floats to a bf16x2 word (compiler emits v_cvt_pk_bf16_f32)
__device__ __forceinline__ u32 pk2(float a, float b) {
  bf16x2 t;
  t[0] = (__bf16)a;
  t[1] = (__bf16)b;
  return __builtin_bit_cast(u32, t);
}

__device__ __forceinline__ void gl16(const void* g, void* l) {
  __builtin_amdgcn_global_load_lds((const __attribute__((address_space(1))) u32*)g,
                                   (__attribute__((address_space(3))) u32*)l, 16, 0, 0);
}

// XOR-swizzle of the 16B-chunk index within a row; involution, applied to both
// the global source (staging) and the LDS read address.
__device__ __forceinline__ int swz(int r, int c) {
  return (c & ~7) | ((c ^ r ^ (r >> 3)) & 7);
}

// ---------------- fp32 -> bf16 elementwise convert (x) ----------------
__global__ __launch_bounds__(256) void k_cvt_bf16(const float* __restrict__ in,
                                                  u16* __restrict__ out, int n4) {
  int i = blockIdx.x * 256 + threadIdx.x;
  if (i < n4) {
    const float4 v = ((const float4*)in)[i];
    ushort4 o;
    o.x = f2bf(v.x); o.y = f2bf(v.y); o.z = f2bf(v.z); o.w = f2bf(v.w);
    ((ushort4*)out)[i] = o;
  }
}

// ---------------- fp32 (K x N) -> bf16 transposed (N x K) ----------------
__global__ __launch_bounds__(256) void k_trans_cvt(const float* __restrict__ W,
                                                   u16* __restrict__ WT,
                                                   int K, int N, int rowoff) {
  __shared__ float tile[32][33];
  const int tx = threadIdx.x, ty = threadIdx.y;
  const int k0 = blockIdx.y * 32, n0 = blockIdx.x * 32;
#pragma unroll
  for (int i = 0; i < 4; ++i)
    tile[ty + 8 * i][tx] = W[(size_t)(k0 + ty + 8 * i) * N + (n0 + tx)];
  __syncthreads();
#pragma unroll
  for (int i = 0; i < 4; ++i)
    WT[(size_t)(rowoff + n0 + ty + 8 * i) * K + (k0 + tx)] = f2bf(tile[tx][ty + 8 * i]);
}

// ---------------- QKV GEMM: x(4096x2048) @ [Wq|Wk|Wv]^T -> qkv bf16, v scattered as V^T ----
__global__ __launch_bounds__(256) void k_gemm_qkv(
    const u16* __restrict__ A, const u16* __restrict__ Bt,
    u16* __restrict__ qkv, u16* __restrict__ vT,
    const float* __restrict__ bq, const float* __restrict__ bk,
    const float* __restrict__ bv) {
  __shared__ u16 As[128 * 32];
  __shared__ u16 Bs[128 * 32];
  const int t = threadIdx.x, l = t & 63, w = t >> 6;
  const int lr = l & 15, lk = l >> 4;
  const int wr = w >> 1, wc = w & 1;
  const int m0 = blockIdx.y * 128, n0 = blockIdx.x * 128;

  f32x4 acc[4][4] = {};

  for (int kt = 0; kt < KD / 32; ++kt) {
    const int k0 = kt * 32;
#pragma unroll
    for (int i = 0; i < 2; ++i) {
      const int e = i * 256 + t;
      const int r = e >> 2, c = (e & 3) << 3;
      gl16(A  + (size_t)(m0 + r) * KD + k0 + c, As + e * 8);
      gl16(Bt + (size_t)(n0 + r) * KD + k0 + c, Bs + e * 8);
    }
    __syncthreads();
    bf16x8 af[4], bfr[4];
#pragma unroll
    for (int m = 0; m < 4; ++m)
      af[m] = *(const bf16x8*)(As + (wr * 64 + m * 16 + lr) * 32 + lk * 8);
#pragma unroll
    for (int n = 0; n < 4; ++n)
      bfr[n] = *(const bf16x8*)(Bs + (wc * 64 + n * 16 + lr) * 32 + lk * 8);
#pragma unroll
    for (int m = 0; m < 4; ++m)
#pragma unroll
      for (int n = 0; n < 4; ++n)
        acc[m][n] = __builtin_amdgcn_mfma_f32_16x16x32_bf16(af[m], bfr[n], acc[m][n], 0, 0, 0);
    __syncthreads();
  }

  const int gm = m0 + wr * 64, gn = n0 + wc * 64;
#pragma unroll
  for (int m = 0; m < 4; ++m) {
    const int row0 = gm + m * 16 + lk * 4;
#pragma unroll
    for (int n = 0; n < 4; ++n) {
      const int col = gn + n * 16 + lr;
      float bias, qs = 1.0f;
      if (col < HID) { bias = bq[col]; qs = QSCALE; }
      else if (col < HID + 512) bias = bk[col - HID];
      else bias = bv[col - HID - 512];
      if (col < HID + 512) {
#pragma unroll
        for (int r = 0; r < 4; ++r)
          qkv[(size_t)(row0 + r) * NQKV + col] = f2bf((acc[m][n][r] + bias) * qs);
      } else {
        const int gg = (col - 2560) >> 7, d = (col - 2560) & 127;
        const int b = row0 >> 11, s0 = row0 & 2047;
        ushort4 pk;
        pk.x = f2bf(acc[m][n][0] + bias);
        pk.y = f2bf(acc[m][n][1] + bias);
        pk.z = f2bf(acc[m][n][2] + bias);
        pk.w = f2bf(acc[m][n][3] + bias);
        *(ushort4*)(vT + ((size_t)(b * GQ + gg) * DH + d) * SEQ + s0) = pk;
      }
    }
  }
}

// ---------------- O projection GEMM: o(4096x2048) @ Wo^T + bo -> fp32 out ----------------
__global__ __launch_bounds__(256) void k_gemm_o(
    const u16* __restrict__ A, const u16* __restrict__ Bt,
    const float* __restrict__ bo, float* __restrict__ C) {
  __shared__ u16 As[128 * 32];
  __shared__ u16 Bs[128 * 32];
  const int t = threadIdx.x, l = t & 63, w = t >> 6;
  const int lr = l & 15, lk = l >> 4;
  const int wr = w >> 1, wc = w & 1;
  const int m0 = blockIdx.y * 128, n0 = blockIdx.x * 128;

  f32x4 acc[4][4] = {};

  for (int kt = 0; kt < KD / 32; ++kt) {
    const int k0 = kt * 32;
#pragma unroll
    for (int i = 0; i < 2; ++i) {
      const int e = i * 256 + t;
      const int r = e >> 2, c = (e & 3) << 3;
      gl16(A  + (size_t)(m0 + r) * KD + k0 + c, As + e * 8);
      gl16(Bt + (size_t)(n0 + r) * KD + k0 + c, Bs + e * 8);
    }
    __syncthreads();
    bf16x8 af[4], bfr[4];
#pragma unroll
    for (int m = 0; m < 4; ++m)
      af[m] = *(const bf16x8*)(As + (wr * 64 + m * 16 + lr) * 32 + lk * 8);
#pragma unroll
    for (int n = 0; n < 4; ++n)
      bfr[n] = *(const bf16x8*)(Bs + (wc * 64 + n * 16 + lr) * 32 + lk * 8);
#pragma unroll
    for (int m = 0; m < 4; ++m)
#pragma unroll
      for (int n = 0; n < 4; ++n)
        acc[m][n] = __builtin_amdgcn_mfma_f32_16x16x32_bf16(af[m], bfr[n], acc[m][n], 0, 0, 0);
    __syncthreads();
  }

  const int gm = m0 + wr * 64, gn = n0 + wc * 64;
#pragma unroll
  for (int m = 0; m < 4; ++m) {
    const int row0 = gm + m * 16 + lk * 4;
#pragma unroll
    for (int n = 0; n < 4; ++n) {
      const int col = gn + n * 16 + lr;
      const float bias = bo[col];
#pragma unroll
      for (int r = 0; r < 4; ++r)
        C[(size_t)(row0 + r) * HID + col] = acc[m][n][r] + bias;
    }
  }
}

// ---------------- Flash attention (swapped QK^T, P fully in registers) ----------------
// Lane layout after mfma(K,Q): sc[nq][mk] holds P^T: q = nq*16+lr, k = mk*16+lk*4+r.
// Softmax: in-lane max over 16 + 2 shfl_xor. P -> PV A-fragment via
// cvt_pk + v_permlane32_swap + v_permlane16_swap (no LDS for P at all).
__global__ __launch_bounds__(256) void k_attn(
    const u16* __restrict__ qkv, const u16* __restrict__ vT, u16* __restrict__ o_ws) {
  __shared__ u16 smem[32768];                 // 64 KiB -> 2 blocks/CU with slack
  u16* const kb0 = smem;                      // 8192 elems (64x128)
  u16* const kb1 = smem + 8192;
  u16* const vb0 = smem + 16384;              // 8192 elems (128x64)
  u16* const vb1 = smem + 24576;

  const int t = threadIdx.x, l = t & 63, w = t >> 6;
  const int lr = l & 15, lk = l >> 4;
  const int bgh = blockIdx.y;
  const int b = bgh >> 4, g = (bgh >> 2) & 3, h = bgh & 3;
  const int q0 = blockIdx.x * 128;
  const int qcol = (g * HPGQ + h) * DH;
  const u16* qbase = qkv + (size_t)(b * SEQ) * NQKV;
  const u16* kbase = qbase + HID + g * DH;
  const u16* vbase = vT + (size_t)(b * GQ + g) * DH * SEQ;

  // stage K/V tile 0 into buffer 0
#pragma unroll
  for (int i = 0; i < 4; ++i) {
    const int e = i * 256 + t;
    const int r = e >> 4, c = e & 15;
    gl16(kbase + (size_t)r * NQKV + swz(r, c) * 8, kb0 + e * 8);
    const int rv = e >> 3, cv = e & 7;
    gl16(vbase + (size_t)rv * SEQ + swz(rv, cv) * 8, vb0 + e * 8);
  }

  // Q fragments: direct global->register (B-operand rows = q, k-contiguous)
  bf16x8 qf[2][4];
#pragma unroll
  for (int nq = 0; nq < 2; ++nq)
#pragma unroll
    for (int kk = 0; kk < 4; ++kk)
      qf[nq][kk] = *(const bf16x8*)(qbase + (size_t)(q0 + w * 32 + nq * 16 + lr) * NQKV +
                                    qcol + kk * 32 + lk * 8);

  __syncthreads();

  f32x4 acc_o[2][8] = {};
  f32x4 acc_s[2] = {};        // row-sum accumulator (valid at lr==0)
  float rm[2] = {-3.0e38f, -3.0e38f};   // running max for q = nq*16 + lr

  bf16x8 vones;               // B-fragment: row 0 (d-col 0) = ones -> row sums
#pragma unroll
  for (int j = 0; j < 8; ++j) vones[j] = (lr == 0) ? (__bf16)1.0f : (__bf16)0.0f;

  for (int tt = 0; tt < SEQ / 64; ++tt) {
    const u16* Ks = (tt & 1) ? kb1 : kb0;
    const u16* Vs = (tt & 1) ? vb1 : vb0;
    // issue next tile's staging into the other buffer (drained at end-of-iter barrier)
    if (tt < SEQ / 64 - 1) {
      const int t0 = (tt + 1) * 64;
      u16* kb = (tt & 1) ? kb0 : kb1;
      u16* vb = (tt & 1) ? vb0 : vb1;
#pragma unroll
      for (int i = 0; i < 4; ++i) {
        const int e = i * 256 + t;
        const int r = e >> 4, c = e & 15;
        gl16(kbase + (size_t)(t0 + r) * NQKV + swz(r, c) * 8, kb + e * 8);
        const int rv = e >> 3, cv = e & 7;
        gl16(vbase + (size_t)rv * SEQ + t0 + swz(rv, cv) * 8, vb + e * 8);
      }
    }

    // scores^T = K Q^T (log2 domain; scale folded into Q)
    f32x4 sc[2][4] = {};
    __builtin_amdgcn_s_setprio(1);
#pragma unroll
    for (int kk = 0; kk < 4; ++kk) {
      bf16x8 kf[4];
#pragma unroll
      for (int mk = 0; mk < 4; ++mk) {
        const int row = mk * 16 + lr;
        kf[mk] = *(const bf16x8*)(Ks + row * 128 + swz(row, kk * 4 + lk) * 8);
      }
#pragma unroll
      for (int nq = 0; nq < 2; ++nq)
#pragma unroll
        for (int mk = 0; mk < 4; ++mk)
          sc[nq][mk] = __builtin_amdgcn_mfma_f32_16x16x32_bf16(kf[mk], qf[nq][kk], sc[nq][mk], 0, 0, 0);
    }
    __builtin_amdgcn_s_setprio(0);

    // per-q max: in-lane over 16 values + 2 shfl_xor across lk groups
    float mx[2];
#pragma unroll
    for (int nq = 0; nq < 2; ++nq) {
      f32x4 m4 = sc[nq][0];
#pragma unroll
      for (int mk = 1; mk < 4; ++mk) {
        m4[0] = fmaxf(m4[0], sc[nq][mk][0]); m4[1] = fmaxf(m4[1], sc[nq][mk][1]);
        m4[2] = fmaxf(m4[2], sc[nq][mk][2]); m4[3] = fmaxf(m4[3], sc[nq][mk][3]);
      }
      float v = fmaxf(fmaxf(m4[0], m4[1]), fmaxf(m4[2], m4[3]));
      v = fmaxf(v, __shfl_xor(v, 16));
      v = fmaxf(v, __shfl_xor(v, 32));
      mx[nq] = v;
    }

    // deferred-max rescale (wave-uniform trigger, THR=11.5 in log2 domain)
    const float dm = fmaxf(mx[0] - rm[0], mx[1] - rm[1]);
    if (__any(dm > 11.5f)) {
#pragma unroll
      for (int nq = 0; nq < 2; ++nq) {
        const float mnew = fmaxf(rm[nq], mx[nq]);
        const float al = FEXP2(rm[nq] - mnew);   // alpha for q = nq*16 + lr
        rm[nq] = mnew;
        // redistribute alpha to accumulator rows q = nq*16 + lk*4 + r
#pragma unroll
        for (int r = 0; r < 4; ++r) {
          const float alq = __shfl(al, ((l >> 4) << 2) + r);
#pragma unroll
          for (int nd = 0; nd < 8; ++nd) acc_o[nq][nd][r] *= alq;
          acc_s[nq][r] *= alq;
        }
      }
    }

    // P = exp2(sc - rm)  (in-lane; rm is this lane's q)
#pragma unroll
    for (int nq = 0; nq < 2; ++nq)
#pragma unroll
      for (int mk = 0; mk < 4; ++mk)
#pragma unroll
        for (int r = 0; r < 4; ++r)
          sc[nq][mk][r] = FEXP2(sc[nq][mk][r] - rm[nq]);

    // O += P V ; row-sum += P . ones  (P routed to A-fragments in registers)
    __builtin_amdgcn_s_setprio(1);
#pragma unroll
    for (int s = 0; s < 2; ++s) {
      bf16x8 pa[2];
#pragma unroll
      for (int nq = 0; nq < 2; ++nq) {
        u32 w0 = pk2(sc[nq][2 * s][0],     sc[nq][2 * s][1]);
        u32 w1 = pk2(sc[nq][2 * s][2],     sc[nq][2 * s][3]);
        u32 w2 = pk2(sc[nq][2 * s + 1][0], sc[nq][2 * s + 1][1]);
        u32 w3 = pk2(sc[nq][2 * s + 1][2], sc[nq][2 * s + 1][3]);
        asm("v_permlane32_swap_b32 %0, %1" : "+v"(w0), "+v"(w2));
        asm("v_permlane32_swap_b32 %0, %1" : "+v"(w1), "+v"(w3));
        asm("v_permlane16_swap_b32 %0, %1" : "+v"(w0), "+v"(w2));
        asm("v_permlane16_swap_b32 %0, %1" : "+v"(w1), "+v"(w3));
        u32x4 u = {w0, w1, w2, w3};
        pa[nq] = __builtin_bit_cast(bf16x8, u);
      }
#pragma unroll
      for (int nq = 0; nq < 2; ++nq)
        acc_s[nq] = __builtin_amdgcn_mfma_f32_16x16x32_bf16(pa[nq], vones, acc_s[nq], 0, 0, 0);
#pragma unroll
      for (int nd = 0; nd < 8; ++nd) {
        const int rowv = nd * 16 + lr;
        const bf16x8 vf = *(const bf16x8*)(Vs + rowv * 64 + swz(rowv, s * 4 + lk) * 8);
#pragma unroll
        for (int nq = 0; nq < 2; ++nq)
          acc_o[nq][nd] = __builtin_amdgcn_mfma_f32_16x16x32_bf16(pa[nq], vf, acc_o[nq][nd], 0, 0, 0);
      }
    }
    __builtin_amdgcn_s_setprio(0);

    __syncthreads();  // drains staging loads + protects buffer swap
  }

  // epilogue: normalize by the MFMA-computed row sums
#pragma unroll
  for (int nq = 0; nq < 2; ++nq)
#pragma unroll
    for (int r = 0; r < 4; ++r) {
      const float s = __shfl(acc_s[nq][r], l & 48);
      const float inv = 1.0f / s;
      const int q = q0 + w * 32 + nq * 16 + lk * 4 + r;
#pragma unroll
      for (int nd = 0; nd < 8; ++nd) {
        const int d = nd * 16 + lr;
        o_ws[(size_t)(b * SEQ + q) * HID + qcol + d] = f2bf(acc_o[nq][nd][r] * inv);
      }
    }
}

extern "C" void kernel_launch(void* const* d_in, const int* in_sizes, int n_in,
                              void* d_out, int out_size, void* d_ws, size_t ws_size,
                              hipStream_t stream) {
  const float* x  = (const float*)d_in[0];
  const float* Wq = (const float*)d_in[1];
  const float* bq = (const float*)d_in[2];
  const float* Wk = (const float*)d_in[3];
  const float* bk = (const float*)d_in[4];
  const float* Wv = (const float*)d_in[5];
  const float* bv = (const float*)d_in[6];
  const float* Wo = (const float*)d_in[7];
  const float* bo = (const float*)d_in[8];
  float* out = (float*)d_out;

  char* ws = (char*)d_ws;
  u16* x_bf  = (u16*)ws;  ws += (size_t)NTOK * KD * 2;        // 16 MiB (reused as o_ws later)
  u16* qkvT  = (u16*)ws;  ws += (size_t)NQKV * KD * 2;        // 12 MiB
  u16* WoT   = (u16*)ws;  ws += (size_t)HID * KD * 2;         //  8 MiB
  u16* qkv   = (u16*)ws;  ws += (size_t)NTOK * NQKV * 2;      // 24 MiB
  u16* vTb   = (u16*)ws;  ws += (size_t)NBATCH * GQ * DH * SEQ * 2;  // 4 MiB
  u16* o_ws  = x_bf;  // x_bf dead after QKV GEMM; attention output reuses it

  k_cvt_bf16<<<(NTOK * KD / 4 + 255) / 256, 256, 0, stream>>>(x, x_bf, NTOK * KD / 4);
  k_trans_cvt<<<dim3(HID / 32, KD / 32), dim3(32, 8), 0, stream>>>(Wq, qkvT, KD, HID, 0);
  k_trans_cvt<<<dim3(512 / 32, KD / 32), dim3(32, 8), 0, stream>>>(Wk, qkvT, KD, 512, 2048);
  k_trans_cvt<<<dim3(512 / 32, KD / 32), dim3(32, 8), 0, stream>>>(Wv, qkvT, KD, 512, 2560);
  k_trans_cvt<<<dim3(HID / 32, KD / 32), dim3(32, 8), 0, stream>>>(Wo, WoT, KD, HID, 0);

  k_gemm_qkv<<<dim3(NQKV / 128, NTOK / 128), 256, 0, stream>>>(x_bf, qkvT, qkv, vTb, bq, bk, bv);
  k_attn<<<dim3(SEQ / 128, NBATCH * GQ * HPGQ), 256, 0, stream>>>(qkv, vTb, o_ws);
  k_gemm_o<<<dim3(HID / 128, NTOK / 128), 256, 0, stream>>>(o_ws, WoT, bo, out);
}